// Round 3
// baseline (329.177 us; speedup 1.0000x reference)
//
#include <hip/hip_runtime.h>
#include <hip/hip_fp16.h>

// out[M,N] = fp16( a[M,K] @ (w_q[K,N] * scale[K/G,N]) ), G=128, all dims 4096.
// Harness dtype contract: fp16 tensors passed/returned as FLOAT32.
// Round 3 change: W-dequant FUSED into the gemm's B-staging (Wt eliminated).
//  - B piece (256n x 32k) staged via 16 coalesced Wq dword loads + 1 scale
//    load per thread (17 vmcnt events), held in a 2-bank reg ping-pong
//    (distance-2 flight), dequanted at write time (0x6400|v hfma2, single
//    rounding) and ds_write_b128'd into the same swizzled slot layout.
//  - vmcnt: per-phase issue [B17, A2]; steady top-of-phase wait vmcnt(21)
//    = A@p-2 + B@p-1 + A@p-1 outstanding. Never drains in the loop.
//  - prep is now only the A f32->f16 copy (96 MiB streaming).
#define MDIM 4096
#define NDIM 4096
#define KDIM 4096
#define NT 256

typedef _Float16 f16x8 __attribute__((ext_vector_type(8)));
typedef float f32x4 __attribute__((ext_vector_type(4)));
typedef unsigned int u32;
typedef unsigned short u16;

__device__ inline __half2 as_half2(u32 u) { return __builtin_bit_cast(__half2, u); }
__device__ inline u32 as_u32(__half2 h) { return __builtin_bit_cast(u32, h); }
// __builtin_amdgcn_cvt_pkrtz returns __fp16 ext_vector(2); bit-cast directly.
__device__ inline u32 pkrtz(float a, float b) {
  return __builtin_bit_cast(u32, __builtin_amdgcn_cvt_pkrtz(a, b));
}

// async global -> LDS, 16 B/lane. LDS dst must be wave-uniform base + lane*16.
__device__ inline void load16_to_lds(const void* g, void* l) {
  __builtin_amdgcn_global_load_lds(
      (__attribute__((address_space(1))) const u32*)g,
      (__attribute__((address_space(3))) u32*)l,
      16, 0, 0);
}

template <int VM>
__device__ __forceinline__ void wait_vmcnt() {
  static_assert(VM == 0 || VM == 2 || VM == 4 || VM == 17 || VM == 21, "");
  if constexpr (VM == 21)
    asm volatile("s_waitcnt vmcnt(21)" ::: "memory");
  else if constexpr (VM == 17)
    asm volatile("s_waitcnt vmcnt(17)" ::: "memory");
  else if constexpr (VM == 4)
    asm volatile("s_waitcnt vmcnt(4)" ::: "memory");
  else if constexpr (VM == 2)
    asm volatile("s_waitcnt vmcnt(2)" ::: "memory");
  else
    asm volatile("s_waitcnt vmcnt(0)" ::: "memory");
}

// ---- prep_a: A fp32 -> fp16 copy (exact: values are fp16-representable) ----
__global__ __launch_bounds__(NT) void prep_a(const float* __restrict__ A,
                                             _Float16* __restrict__ A16) {
  const size_t base = ((size_t)blockIdx.x * NT + threadIdx.x) * 8;
  const float4 f0 = *(const float4*)(A + base);
  const float4 f1 = *(const float4*)(A + base + 4);
  u32 pk[4];
  pk[0] = pkrtz(f0.x, f0.y);
  pk[1] = pkrtz(f0.z, f0.w);
  pk[2] = pkrtz(f1.x, f1.y);
  pk[3] = pkrtz(f1.z, f1.w);
  *(uint4*)(A16 + base) = *(const uint4*)pk;
}

// ------- 256x256 counted-vmcnt pipelined GEMM with fused W-dequant -------
// LDS: ring of 4 slots per operand, slot = [256 rows][32 k] f16 (16 KB).
// A: global_load_lds, source-swizzled (phys chunk = logical ^ ((row>>1)&3)),
//    issued at phase p for piece p+3.
// B: piece q = Wq ints loaded (coalesced along n) at phase q-4 into a reg
//    bank, dequanted + ds_write (swizzled) at phase q-2, read at phase q.
//    Bank ping-pong: piece q uses bank q&1; each phase touches one bank.
// Phase p: wait vmcnt -> barrier -> 12 frag ds_read_b128 -> writeB(p+2) ->
//    issueB(p+4) -> issueA(p+3) -> lgkmcnt(0) -> 32 MFMA (setprio-wrapped).
__global__ __launch_bounds__(512, 2) void gemm_f16(const _Float16* __restrict__ A16,
                                                   const int* __restrict__ Wq,
                                                   const float* __restrict__ Sc,
                                                   float* __restrict__ C) {
  __shared__ __align__(16) _Float16 As[4 * 256 * 32];  // 64 KB
  __shared__ __align__(16) _Float16 Bs[4 * 256 * 32];  // 64 KB

  const int tid = threadIdx.x;
  const int bx = blockIdx.x & 15;  // n-block
  const int by = blockIdx.x >> 4;  // m-block
  const int m_base = by * 256;
  const int n_base = bx * 256;

  const int wave = tid >> 6;
  const int lane = tid & 63;
  const int l15 = lane & 15;
  const int quad = lane >> 4;
  const int mq = wave >> 2;  // 0..1 : 128-row band
  const int nq = wave & 3;   // 0..3 : 64-col band
  const int gq = (l15 >> 1) & 3;  // row-swizzle term (row ≡ l15 mod 16)
  const int pchunk = quad ^ gq;   // physical 16B chunk for frag reads

  // B-staging geometry: thread owns n = tid&255, k-half kh = (tid>>8)*16.
  const int bn = tid & 255;
  const int kh = (tid >> 8) * 16;
  const int swzn = (bn >> 1) & 3;
  const int c0p = (kh >> 3) ^ swzn;  // phys chunk for pk[0..3]; ^1 for pk[4..7]
  const int* const wq_col = Wq + n_base + bn;
  const float* const sc_col = Sc + n_base + bn;

  f32x4 acc[8][4];
#pragma unroll
  for (int i = 0; i < 8; ++i)
#pragma unroll
    for (int j = 0; j < 4; ++j) acc[i][j] = (f32x4)0.0f;

  int vb0[16], vb1[16];
  float sc0, sc1;

  // issue 16 Wq dwords + 1 scale for piece q into a bank (17 vmcnt events)
  auto issueB = [&](int q, int(&vb)[16], float& sc) {
    const int* src = wq_col + (size_t)(q * 32 + kh) * NDIM;
#pragma unroll
    for (int l = 0; l < 16; ++l) vb[l] = src[(size_t)l * NDIM];
    sc = sc_col[(size_t)(q >> 2) * NDIM];
  };

  // dequant bank -> ds_write piece q into slot q&3 (swizzled layout)
  auto writeB = [&](int q, int(&vb)[16], float sc) {
    const __half hs = __float2half(sc);
    const __half2 s2 = __half2half2(hs);
    const __half2 nb = __half2half2(__hmul(hs, __float2half(-1024.0f)));
    u32 pk[8];
#pragma unroll
    for (int l = 0; l < 8; ++l) {
      // fp16 bits of (1024+v): 0x6400|v; hfma gives single-rounded v*s.
      const u32 u = (u32)vb[2 * l] | ((u32)vb[2 * l + 1] << 16) | 0x64006400u;
      pk[l] = as_u32(__hfma2(as_half2(u), s2, nb));
    }
    char* slotb = (char*)Bs + (size_t)(q & 3) * 16384 + (size_t)bn * 64;
    *(uint4*)(slotb + c0p * 16) = *(const uint4*)&pk[0];
    *(uint4*)(slotb + (c0p ^ 1) * 16) = *(const uint4*)&pk[4];
  };

  // A piece q via global_load_lds into slot q&3 (2 vmcnt events)
  auto issueA = [&](int q) {
    const size_t kof = (size_t)q * 32;
    const int s = q & 3;
#pragma unroll
    for (int L = 0; L < 2; ++L) {
      const int cc = L * 512 + tid;  // 0..1023 : (row, phys chunk)
      const int row = cc >> 2;
      const int lch = (cc & 3) ^ ((row >> 1) & 3);
      load16_to_lds(A16 + (size_t)(m_base + row) * KDIM + kof + lch * 8,
                    (char*)As + (size_t)s * 16384 + (size_t)cc * 16);
    }
  };

  // caller performs the top-of-phase wait_vmcnt BEFORE calling.
  auto phase = [&](int p, int(&vb)[16], float& sc, bool dw, bool dib, bool dia) {
    __builtin_amdgcn_s_barrier();
    asm volatile("" ::: "memory");  // no LDS access hoists above the barrier
    const int s = p & 3;
    const _Float16* Ab = (const _Float16*)((const char*)As + (size_t)s * 16384);
    const _Float16* Bb = (const _Float16*)((const char*)Bs + (size_t)s * 16384);
    f16x8 af[8], bf[4];
#pragma unroll
    for (int i = 0; i < 8; ++i) {
      const int row = mq * 128 + i * 16 + l15;
      af[i] = *(const f16x8*)(Ab + (size_t)row * 32 + pchunk * 8);
    }
#pragma unroll
    for (int j = 0; j < 4; ++j) {
      const int row = nq * 64 + j * 16 + l15;
      bf[j] = *(const f16x8*)(Bb + (size_t)row * 32 + pchunk * 8);
    }
    if (dw) writeB(p + 2, vb, sc);   // consumes bank regs
    if (dib) issueB(p + 4, vb, sc);  // refills same bank
    if (dia) issueA(p + 3);
    asm volatile("s_waitcnt lgkmcnt(0)" ::: "memory");
    __builtin_amdgcn_sched_barrier(0);  // keep MFMAs below the wait (rule 18)
    __builtin_amdgcn_s_setprio(1);
#pragma unroll
    for (int i = 0; i < 8; ++i)
#pragma unroll
      for (int j = 0; j < 4; ++j)
        acc[i][j] = __builtin_amdgcn_mfma_f32_16x16x32_f16(af[i], bf[j],
                                                           acc[i][j], 0, 0, 0);
    __builtin_amdgcn_s_setprio(0);
  };

  // ---- prologue: B0,B1 loaded+written; B2,B3 in flight; A0..A2 in flight.
  issueB(0, vb0, sc0);            // 17
  issueB(1, vb1, sc1);            // 34
  wait_vmcnt<17>();               // B0 landed
  writeB(0, vb0, sc0);
  issueB(2, vb0, sc0);            // bank0 = piece 2 (q&1==0)
  wait_vmcnt<17>();               // B1 landed (B2 still in flight)
  writeB(1, vb1, sc1);
  issueB(3, vb1, sc1);            // bank1 = piece 3
  issueA(0);
  issueA(1);
  issueA(2);                      // outstanding: B2+B3+A0..A2 = 40

  // ---- 128 phases = 64 K-tiles x 2 k-halves.
  // waits: p0 needs A0 (newer: A1,A2 = 4; covers B2,B3 which are older).
  // p in 1..124: need B@p-2 (for write) and A@p-3 (piece p in LDS):
  //   newer than B@p-2 = A@p-2(2) + B@p-1(17) + A@p-1(2) = 21.
  // tail: p125 -> 4, p126 -> 2, p127 -> 0.
  wait_vmcnt<4>();
  phase(0, vb0, sc0, true, true, true);
  for (int p = 1; p < 123; p += 2) {
    wait_vmcnt<21>();
    phase(p, vb1, sc1, true, true, true);
    wait_vmcnt<21>();
    phase(p + 1, vb0, sc0, true, true, true);
  }
  wait_vmcnt<21>();
  phase(123, vb1, sc1, true, true, true);   // writes 125, issues B127, A126
  wait_vmcnt<21>();
  phase(124, vb0, sc0, true, false, true);  // writes 126, issues A127
  wait_vmcnt<4>();
  phase(125, vb1, sc1, true, false, false); // writes 127
  wait_vmcnt<2>();
  phase(126, vb0, sc0, false, false, false);
  wait_vmcnt<0>();
  phase(127, vb1, sc1, false, false, false);

  // epilogue: C/D layout col=lane&15, row=quad*4+reg; fp16-round, store f32
#pragma unroll
  for (int i = 0; i < 8; ++i) {
#pragma unroll
    for (int j = 0; j < 4; ++j) {
      const int col = n_base + nq * 64 + j * 16 + l15;
#pragma unroll
      for (int r = 0; r < 4; ++r) {
        const int row = m_base + mq * 128 + i * 16 + quad * 4 + r;
        C[(size_t)row * NDIM + col] = __half2float(__float2half(acc[i][j][r]));
      }
    }
  }
}

// ---------------- fallback: fused single-kernel (round-3, 331 us) --------
#define STR 72
__global__ __launch_bounds__(NT) void qgemm_fused(
    const float* __restrict__ A, const int* __restrict__ Wq,
    const float* __restrict__ Sc, float* __restrict__ C) {
  __shared__ __align__(16) _Float16 As[128 * STR];
  __shared__ __align__(16) _Float16 Bs[128 * STR];
  const int tid = threadIdx.x;
  const int bx = blockIdx.x & 31, by = blockIdx.x >> 5;
  const int m_base = by * 128, n_base = bx * 128;
  const int wave = tid >> 6, lane = tid & 63;
  const int l15 = lane & 15, quad = lane >> 4;
  const int wm = (wave & 1) * 64, wn = (wave >> 1) * 64;
  const int bn_local = tid & 127, bk_half = (tid >> 7) * 8;
  const int gn = n_base + bn_local;
  f32x4 acc[4][4];
#pragma unroll
  for (int i = 0; i < 4; ++i)
#pragma unroll
    for (int j = 0; j < 4; ++j) acc[i][j] = (f32x4)0.0f;
  for (int kt = 0; kt < KDIM / 64; ++kt) {
    const int k0 = kt * 64;
    __syncthreads();
#pragma unroll
    for (int i = 0; i < 8; ++i) {
      const int c = i * 256 + tid;
      const int row = c >> 4, col4 = (c & 15) * 4;
      const float4 f = *(const float4*)(A + (size_t)(m_base + row) * KDIM + k0 + col4);
      u32 pk[2];
      pk[0] = pkrtz(f.x, f.y);
      pk[1] = pkrtz(f.z, f.w);
      *(uint2*)&As[(size_t)row * STR + col4] = *(const uint2*)pk;
    }
    {
      const __half hs = __float2half(Sc[(size_t)(k0 >> 7) * NDIM + gn]);
      const __half2 s2 = __half2half2(hs);
      const __half2 nb2 = __half2half2(__hmul(hs, __float2half(-1024.0f)));
#pragma unroll
      for (int it = 0; it < 4; ++it) {
        const int k = bk_half + it * 16;
        u32 v[8];
#pragma unroll
        for (int j = 0; j < 8; ++j)
          v[j] = (u32)Wq[(size_t)(k0 + k + j) * NDIM + gn];
        u32 pk[4];
#pragma unroll
        for (int p = 0; p < 4; ++p) {
          u32 u = v[2 * p] | (v[2 * p + 1] << 16) | 0x64006400u;
          pk[p] = as_u32(__hfma2(as_half2(u), s2, nb2));
        }
        *(uint4*)&Bs[(size_t)bn_local * STR + k] = *(const uint4*)pk;
      }
    }
    __syncthreads();
#pragma unroll
    for (int ks = 0; ks < 64; ks += 32) {
      f16x8 af[4], bf[4];
#pragma unroll
      for (int i = 0; i < 4; ++i)
        af[i] = *(const f16x8*)&As[(size_t)(wm + i * 16 + l15) * STR + ks + quad * 8];
#pragma unroll
      for (int j = 0; j < 4; ++j)
        bf[j] = *(const f16x8*)&Bs[(size_t)(wn + j * 16 + l15) * STR + ks + quad * 8];
#pragma unroll
      for (int i = 0; i < 4; ++i)
#pragma unroll
        for (int j = 0; j < 4; ++j)
          acc[i][j] = __builtin_amdgcn_mfma_f32_16x16x32_f16(af[i], bf[j],
                                                             acc[i][j], 0, 0, 0);
    }
  }
#pragma unroll
  for (int i = 0; i < 4; ++i)
#pragma unroll
    for (int j = 0; j < 4; ++j) {
      const int col = n_base + wn + j * 16 + l15;
#pragma unroll
      for (int r = 0; r < 4; ++r) {
        const int row = m_base + wm + i * 16 + quad * 4 + r;
        C[(size_t)row * NDIM + col] = __half2float(__float2half(acc[i][j][r]));
      }
    }
}

extern "C" void kernel_launch(void* const* d_in, const int* in_sizes, int n_in,
                              void* d_out, int out_size, void* d_ws, size_t ws_size,
                              hipStream_t stream) {
  const float* a = (const float*)d_in[0];
  const int* wq = (const int*)d_in[1];
  const float* sc = (const float*)d_in[2];
  float* out = (float*)d_out;

  const size_t a16_bytes = (size_t)MDIM * KDIM * 2;  // 32 MiB

  if (ws_size >= a16_bytes) {
    _Float16* a16 = (_Float16*)d_ws;
    prep_a<<<(MDIM * KDIM) / (NT * 8), NT, 0, stream>>>(a, a16);
    gemm_f16<<<(MDIM / 256) * (NDIM / 256), 512, 0, stream>>>(a16, wq, sc, out);
  } else {
    qgemm_fused<<<(MDIM / 128) * (NDIM / 128), NT, 0, stream>>>(a, wq, sc, out);
  }
}

// Round 4
// 285.874 us; speedup vs baseline: 1.1515x; 1.1515x over previous
//
#include <hip/hip_runtime.h>
#include <hip/hip_fp16.h>

// out[M,N] = fp16( a[M,K] @ (w_q[K,N] * scale[K/G,N]) ), G=128, all dims 4096.
// Harness dtype contract: fp16 tensors passed/returned as FLOAT32.
// Round 4: revert round-3's fused B-dequant (VMEM-issue bound, 28% MfmaUtil).
// Back to round-2 structure (prep: A-copy + W dequant/transpose -> Wt; gemm
// reads A16/Wt via global_load_lds ring). NEW: intra-phase fine interleave -
// issue the 12 frag ds_read_b128 in order (af01, bf0..3, af2..7), then
// counted lgkmcnt(6/4/2/0) waits split the 32 MFMAs into 4 clusters of 8,
// overlapping remaining LDS reads with MFMA within the wave (m201 T3).
#define MDIM 4096
#define NDIM 4096
#define KDIM 4096
#define NT 256
#define WBLK 4096

typedef _Float16 f16x8 __attribute__((ext_vector_type(8)));
typedef float f32x4 __attribute__((ext_vector_type(4)));
typedef unsigned int u32;
typedef unsigned short u16;

__device__ inline __half2 as_half2(u32 u) { return __builtin_bit_cast(__half2, u); }
__device__ inline u32 as_u32(__half2 h) { return __builtin_bit_cast(u32, h); }
// __builtin_amdgcn_cvt_pkrtz returns __fp16 ext_vector(2); bit-cast directly.
__device__ inline u32 pkrtz(float a, float b) {
  return __builtin_bit_cast(u32, __builtin_amdgcn_cvt_pkrtz(a, b));
}

// async global -> LDS, 16 B/lane. LDS dst must be wave-uniform base + lane*16.
__device__ inline void load16_to_lds(const void* g, void* l) {
  __builtin_amdgcn_global_load_lds(
      (__attribute__((address_space(1))) const u32*)g,
      (__attribute__((address_space(3))) u32*)l,
      16, 0, 0);
}

template <int VM>
__device__ __forceinline__ void wait_vmcnt() {
  if constexpr (VM == 8)
    asm volatile("s_waitcnt vmcnt(8)" ::: "memory");
  else if constexpr (VM == 4)
    asm volatile("s_waitcnt vmcnt(4)" ::: "memory");
  else
    asm volatile("s_waitcnt vmcnt(0)" ::: "memory");
}

template <int LK>
__device__ __forceinline__ void wait_lgkm() {
  if constexpr (LK == 6)
    asm volatile("s_waitcnt lgkmcnt(6)" ::: "memory");
  else if constexpr (LK == 4)
    asm volatile("s_waitcnt lgkmcnt(4)" ::: "memory");
  else if constexpr (LK == 2)
    asm volatile("s_waitcnt lgkmcnt(2)" ::: "memory");
  else
    asm volatile("s_waitcnt lgkmcnt(0)" ::: "memory");
  __builtin_amdgcn_sched_barrier(0);  // keep MFMAs below the wait (rule 18)
}

// ---- fused prepass: blocks [0,4096) dequant+transpose W, rest copy A ----
__global__ __launch_bounds__(NT) void prep(const float* __restrict__ A,
                                           _Float16* __restrict__ A16,
                                           const int* __restrict__ Wq,
                                           const float* __restrict__ Sc,
                                           _Float16* __restrict__ Wt) {
  // u32 staging [n][k-pair], stride 33 dwords: write bank (n+kp)%32 (2-way),
  // read bank (n+k2c+j)%32 (2-way). 8.25 KB -> high occupancy.
  __shared__ u32 Lt[64 * 33];
  const int tid = threadIdx.x;

  if (blockIdx.x >= WBLK) {
    // ---- A fp32 -> fp16 (exact: values are fp16-representable) ----
    const size_t b = blockIdx.x - WBLK;
    const size_t base = (b * NT + tid) * 8;
    const float4 f0 = *(const float4*)(A + base);
    const float4 f1 = *(const float4*)(A + base + 4);
    u32 pk[4];
    pk[0] = pkrtz(f0.x, f0.y);
    pk[1] = pkrtz(f0.z, f0.w);
    pk[2] = pkrtz(f1.x, f1.y);
    pk[3] = pkrtz(f1.z, f1.w);
    *(uint4*)(A16 + base) = *(const uint4*)pk;
    return;
  }

  // ---- W: dequant Wq [K][N] + transpose -> Wt f16 [N][K], 64x64 tile ----
  const int n0 = (blockIdx.x & 63) * 64;
  const int k0 = (blockIdx.x >> 6) * 64;
  const int g = k0 >> 7;  // 64-tile lies within one 128-group

  // phase 1: coalesced read of two adjacent k-rows, dequant to packed k-pair
#pragma unroll
  for (int r = 0; r < 2; ++r) {
    const int idx = r * 256 + tid;
    const int kp = idx >> 4;          // k-pair index 0..31
    const int col4 = (idx & 15) * 4;  // n within tile, 4 at a time
    const int4 va = *(const int4*)(Wq + (size_t)(k0 + 2 * kp) * NDIM + n0 + col4);
    const int4 vb = *(const int4*)(Wq + (size_t)(k0 + 2 * kp + 1) * NDIM + n0 + col4);
    const float4 s = *(const float4*)(Sc + (size_t)g * NDIM + n0 + col4);
    const float sf[4] = {s.x, s.y, s.z, s.w};
    const int av[4] = {va.x, va.y, va.z, va.w};
    const int bv[4] = {vb.x, vb.y, vb.z, vb.w};
#pragma unroll
    for (int i = 0; i < 4; ++i) {
      // fp16 bits of (1024+v): 0x6400|v; hfma gives single-rounded v*s.
      const __half hs = __float2half(sf[i]);
      const __half2 s2 = __half2half2(hs);
      const __half2 nb = __half2half2(__hmul(hs, __float2half(-1024.0f)));
      const u32 u = (u32)av[i] | ((u32)bv[i] << 16) | 0x64006400u;
      // u32 holds (w[2kp]*s, w[2kp+1]*s) = the contiguous k-pair for Wt[n].
      Lt[(size_t)(col4 + i) * 33 + kp] = as_u32(__hfma2(as_half2(u), s2, nb));
    }
  }
  __syncthreads();

  // phase 2: gather 4 k-pair dwords per thread, coalesced 16B writes to Wt
#pragma unroll
  for (int r = 0; r < 2; ++r) {
    const int idx = r * 256 + tid;
    const int n = idx >> 3;          // 0..63
    const int k2c = (idx & 7) * 4;   // dword column 0..28 (= k/2)
    u32 v[4];
#pragma unroll
    for (int j = 0; j < 4; ++j) v[j] = Lt[(size_t)n * 33 + k2c + j];
    *(uint4*)(Wt + (size_t)(n0 + n) * KDIM + k0 + k2c * 2) = *(const uint4*)v;
  }
}

// ---------------- 256x256 counted-vmcnt pipelined f16 GEMM ----------------
// LDS: ring of 4 slots per operand, each slot = one k-half piece
//   [256 rows][4 phys chunks of 16B] (16 KB). Phase p uses slot p&3 and
//   stages the piece for phase p+3 into slot (p+3)&3 (last read at p-1,
//   whose reads completed before any wave could pass p's entry barrier).
// Swizzle: physical chunk = logical ^ ((row>>1)&3). Applied to the per-lane
// GLOBAL source (LDS dst stays linear for global_load_lds), and to the
// ds_read_b128 fragment address -> balanced 8 dwords/bank, no conflicts.
// Intra-phase: reads issued af01,bf0..3,af2..7; counted lgkmcnt(6/4/2/0)
// splits 32 MFMA into 4x8 clusters overlapping the in-flight af reads.
__global__ __launch_bounds__(512, 2) void gemm_f16(const _Float16* __restrict__ A16,
                                                   const _Float16* __restrict__ Wt,
                                                   float* __restrict__ C) {
  __shared__ __align__(16) _Float16 As[4 * 256 * 32];  // 64 KB
  __shared__ __align__(16) _Float16 Bs[4 * 256 * 32];  // 64 KB

  const int tid = threadIdx.x;
  const int bx = blockIdx.x & 15;  // n-block
  const int by = blockIdx.x >> 4;  // m-block
  const int m_base = by * 256;
  const int n_base = bx * 256;

  const int wave = tid >> 6;
  const int lane = tid & 63;
  const int l15 = lane & 15;
  const int quad = lane >> 4;
  const int mq = wave >> 2;  // 0..1 : 128-row band
  const int nq = wave & 3;   // 0..3 : 64-col band
  const int gq = (l15 >> 1) & 3;       // row-swizzle term (row ≡ l15 mod 16)
  const int pchunk = quad ^ gq;        // physical 16B chunk for frag reads

  f32x4 acc[8][4];
#pragma unroll
  for (int i = 0; i < 8; ++i)
#pragma unroll
    for (int j = 0; j < 4; ++j) acc[i][j] = (f32x4)0.0f;

  // stage pieces (A khalf + B khalf) for phase p into slot p&3.
  // 2+2 global_load_lds per thread = 4 vmcnt events per wave per stage.
  auto stage = [&](int p) {
    const int T = p >> 1;        // K-tile
    const int h = p & 1;         // k-half within tile
    const int s = p & 3;         // slot
    const size_t kof = (size_t)T * 64 + (size_t)h * 32;
#pragma unroll
    for (int L = 0; L < 2; ++L) {
      const int cc = L * 512 + tid;        // 0..1023 : (row, phys chunk)
      const int row = cc >> 2;
      const int lch = (cc & 3) ^ ((row >> 1) & 3);  // logical chunk at phys cc&3
      load16_to_lds(A16 + (size_t)(m_base + row) * KDIM + kof + lch * 8,
                    (char*)As + (size_t)s * 16384 + (size_t)cc * 16);
    }
#pragma unroll
    for (int L = 0; L < 2; ++L) {
      const int cc = L * 512 + tid;
      const int row = cc >> 2;
      const int lch = (cc & 3) ^ ((row >> 1) & 3);
      load16_to_lds(Wt + (size_t)(n_base + row) * KDIM + kof + lch * 8,
                    (char*)Bs + (size_t)s * 16384 + (size_t)cc * 16);
    }
  };

  auto phase_body = [&](int p, bool dostage) {
    __builtin_amdgcn_s_barrier();
    asm volatile("" ::: "memory");  // no LDS access hoists above the barrier
    const int s = p & 3;
    const _Float16* Ab = (const _Float16*)((const char*)As + (size_t)s * 16384);
    const _Float16* Bb = (const _Float16*)((const char*)Bs + (size_t)s * 16384);
    f16x8 af[8], bf[4];
    // issue order matters for the counted waits (DS retires in order):
    // af0, af1, bf0..3, af2..af7  (12 ds_read_b128)
#pragma unroll
    for (int i = 0; i < 2; ++i) {
      const int row = mq * 128 + i * 16 + l15;
      af[i] = *(const f16x8*)(Ab + (size_t)row * 32 + pchunk * 8);
    }
#pragma unroll
    for (int j = 0; j < 4; ++j) {
      const int row = nq * 64 + j * 16 + l15;
      bf[j] = *(const f16x8*)(Bb + (size_t)row * 32 + pchunk * 8);
    }
#pragma unroll
    for (int i = 2; i < 8; ++i) {
      const int row = mq * 128 + i * 16 + l15;
      af[i] = *(const f16x8*)(Ab + (size_t)row * 32 + pchunk * 8);
    }
    if (dostage) stage(p + 3);  // VMEM issue overlaps the MFMA clusters

    // cluster q: rows i=2q,2q+1 x all j, while af[2q+2..] still in flight
    wait_lgkm<6>();  // af0,af1,bf0..3 retired
    __builtin_amdgcn_s_setprio(1);
#pragma unroll
    for (int i = 0; i < 2; ++i)
#pragma unroll
      for (int j = 0; j < 4; ++j)
        acc[i][j] = __builtin_amdgcn_mfma_f32_16x16x32_f16(af[i], bf[j],
                                                           acc[i][j], 0, 0, 0);
    __builtin_amdgcn_s_setprio(0);
    wait_lgkm<4>();  // af2,af3 retired
    __builtin_amdgcn_s_setprio(1);
#pragma unroll
    for (int i = 2; i < 4; ++i)
#pragma unroll
      for (int j = 0; j < 4; ++j)
        acc[i][j] = __builtin_amdgcn_mfma_f32_16x16x32_f16(af[i], bf[j],
                                                           acc[i][j], 0, 0, 0);
    __builtin_amdgcn_s_setprio(0);
    wait_lgkm<2>();  // af4,af5 retired
    __builtin_amdgcn_s_setprio(1);
#pragma unroll
    for (int i = 4; i < 6; ++i)
#pragma unroll
      for (int j = 0; j < 4; ++j)
        acc[i][j] = __builtin_amdgcn_mfma_f32_16x16x32_f16(af[i], bf[j],
                                                           acc[i][j], 0, 0, 0);
    __builtin_amdgcn_s_setprio(0);
    wait_lgkm<0>();  // af6,af7 retired
    __builtin_amdgcn_s_setprio(1);
#pragma unroll
    for (int i = 6; i < 8; ++i)
#pragma unroll
      for (int j = 0; j < 4; ++j)
        acc[i][j] = __builtin_amdgcn_mfma_f32_16x16x32_f16(af[i], bf[j],
                                                           acc[i][j], 0, 0, 0);
    __builtin_amdgcn_s_setprio(0);
  };

  // prologue: pieces for phases 0,1,2 (12 vmcnt events in flight)
  stage(0);
  stage(1);
  stage(2);

  // 128 phases = 64 K-tiles x 2 k-halves. vmcnt(8): phases p-1,p-2 in
  // flight, phase p's pieces (staged at p-3) guaranteed landed before the
  // entry barrier (all waves execute the wait pre-barrier).
  for (int p = 0; p < 125; ++p) {
    wait_vmcnt<8>();
    phase_body(p, true);
  }
  wait_vmcnt<8>();
  phase_body(125, false);
  wait_vmcnt<4>();
  phase_body(126, false);
  wait_vmcnt<0>();
  phase_body(127, false);

  // epilogue: C/D layout col=lane&15, row=quad*4+reg; fp16-round, store f32
#pragma unroll
  for (int i = 0; i < 8; ++i) {
#pragma unroll
    for (int j = 0; j < 4; ++j) {
      const int col = n_base + nq * 64 + j * 16 + l15;
#pragma unroll
      for (int r = 0; r < 4; ++r) {
        const int row = m_base + mq * 128 + i * 16 + quad * 4 + r;
        C[(size_t)row * NDIM + col] = __half2float(__float2half(acc[i][j][r]));
      }
    }
  }
}

// ---------------- fallback: fused single-kernel (round-3, 331 us) --------
#define STR 72
__global__ __launch_bounds__(NT) void qgemm_fused(
    const float* __restrict__ A, const int* __restrict__ Wq,
    const float* __restrict__ Sc, float* __restrict__ C) {
  __shared__ __align__(16) _Float16 As[128 * STR];
  __shared__ __align__(16) _Float16 Bs[128 * STR];
  const int tid = threadIdx.x;
  const int bx = blockIdx.x & 31, by = blockIdx.x >> 5;
  const int m_base = by * 128, n_base = bx * 128;
  const int wave = tid >> 6, lane = tid & 63;
  const int l15 = lane & 15, quad = lane >> 4;
  const int wm = (wave & 1) * 64, wn = (wave >> 1) * 64;
  const int bn_local = tid & 127, bk_half = (tid >> 7) * 8;
  const int gn = n_base + bn_local;
  f32x4 acc[4][4];
#pragma unroll
  for (int i = 0; i < 4; ++i)
#pragma unroll
    for (int j = 0; j < 4; ++j) acc[i][j] = (f32x4)0.0f;
  for (int kt = 0; kt < KDIM / 64; ++kt) {
    const int k0 = kt * 64;
    __syncthreads();
#pragma unroll
    for (int i = 0; i < 8; ++i) {
      const int c = i * 256 + tid;
      const int row = c >> 4, col4 = (c & 15) * 4;
      const float4 f = *(const float4*)(A + (size_t)(m_base + row) * KDIM + k0 + col4);
      u32 pk[2];
      pk[0] = pkrtz(f.x, f.y);
      pk[1] = pkrtz(f.z, f.w);
      *(uint2*)&As[(size_t)row * STR + col4] = *(const uint2*)pk;
    }
    {
      const __half hs = __float2half(Sc[(size_t)(k0 >> 7) * NDIM + gn]);
      const __half2 s2 = __half2half2(hs);
      const __half2 nb2 = __half2half2(__hmul(hs, __float2half(-1024.0f)));
#pragma unroll
      for (int it = 0; it < 4; ++it) {
        const int k = bk_half + it * 16;
        u32 v[8];
#pragma unroll
        for (int j = 0; j < 8; ++j)
          v[j] = (u32)Wq[(size_t)(k0 + k + j) * NDIM + gn];
        u32 pk[4];
#pragma unroll
        for (int p = 0; p < 4; ++p) {
          u32 u = v[2 * p] | (v[2 * p + 1] << 16) | 0x64006400u;
          pk[p] = as_u32(__hfma2(as_half2(u), s2, nb2));
        }
        *(uint4*)&Bs[(size_t)bn_local * STR + k] = *(const uint4*)pk;
      }
    }
    __syncthreads();
#pragma unroll
    for (int ks = 0; ks < 64; ks += 32) {
      f16x8 af[4], bf[4];
#pragma unroll
      for (int i = 0; i < 4; ++i)
        af[i] = *(const f16x8*)&As[(size_t)(wm + i * 16 + l15) * STR + ks + quad * 8];
#pragma unroll
      for (int j = 0; j < 4; ++j)
        bf[j] = *(const f16x8*)&Bs[(size_t)(wn + j * 16 + l15) * STR + ks + quad * 8];
#pragma unroll
      for (int i = 0; i < 4; ++i)
#pragma unroll
        for (int j = 0; j < 4; ++j)
          acc[i][j] = __builtin_amdgcn_mfma_f32_16x16x32_f16(af[i], bf[j],
                                                             acc[i][j], 0, 0, 0);
    }
  }
#pragma unroll
  for (int i = 0; i < 4; ++i)
#pragma unroll
    for (int j = 0; j < 4; ++j) {
      const int col = n_base + wn + j * 16 + l15;
#pragma unroll
      for (int r = 0; r < 4; ++r) {
        const int row = m_base + wm + i * 16 + quad * 4 + r;
        C[(size_t)row * NDIM + col] = __half2float(__float2half(acc[i][j][r]));
      }
    }
}

extern "C" void kernel_launch(void* const* d_in, const int* in_sizes, int n_in,
                              void* d_out, int out_size, void* d_ws, size_t ws_size,
                              hipStream_t stream) {
  const float* a = (const float*)d_in[0];
  const int* wq = (const int*)d_in[1];
  const float* sc = (const float*)d_in[2];
  float* out = (float*)d_out;

  const size_t a16_bytes = (size_t)MDIM * KDIM * 2;  // 32 MiB
  const size_t wt_bytes = (size_t)NDIM * KDIM * 2;   // 32 MiB

  if (ws_size >= a16_bytes + wt_bytes) {
    _Float16* a16 = (_Float16*)d_ws;
    _Float16* wt = (_Float16*)((char*)d_ws + a16_bytes);
    const int a_blocks = (MDIM * KDIM) / (NT * 8);  // 8192
    prep<<<WBLK + a_blocks, NT, 0, stream>>>(a, a16, wq, sc, wt);
    gemm_f16<<<(MDIM / 256) * (NDIM / 256), 512, 0, stream>>>(a16, wt, out);
  } else {
    qgemm_fused<<<(MDIM / 128) * (NDIM / 128), NT, 0, stream>>>(a, wq, sc, out);
  }
}